// Round 1
// baseline (439.334 us; speedup 1.0000x reference)
//
#include <hip/hip_runtime.h>

// ParallelExperts MoE: out[t] = sum_j gates[t,j] * inputs[t] @ weight[e_{t,j}]^T
// N=262144 tokens, k=2, E=8, d_in=d_out=128.
// Strategy: process sorted positions in blocks of 128 (expert-uniform except at
// ~7 run boundaries), gather A rows to LDS as f16, MFMA 16x16x32_f16 against
// weight[e] (B-frags loaded from global, L2-hot), scatter g*y via atomicAdd.

#define D       128
#define TILE_P  128
#define LSTR    136      // LDS row stride (f16 elems): 272 B = 17*16 B -> 16B-aligned rows, 2-way bank pattern
#define NTOK    262144
#define NK      (NTOK * 2)

typedef _Float16 halfx8 __attribute__((ext_vector_type(8)));
typedef _Float16 halfx4 __attribute__((ext_vector_type(4)));
typedef float    floatx4 __attribute__((ext_vector_type(4)));

__global__ __launch_bounds__(256, 2)
void moe_mfma_kernel(const float* __restrict__ inputs,
                     const float* __restrict__ weight,
                     const float* __restrict__ gates,
                     const int*   __restrict__ sei,
                     const int*   __restrict__ ssi,
                     float*       __restrict__ out)
{
    __shared__ _Float16 As[TILE_P * LSTR];   // gathered token rows, f16
    __shared__ int   toks[TILE_P];
    __shared__ float gts[TILE_P];
    __shared__ int   eids[TILE_P];

    const int tid = threadIdx.x;
    const int p0  = blockIdx.x * TILE_P;

    // Per-row metadata: slot -> token, gate, expert
    if (tid < TILE_P) {
        int s = ssi[p0 + tid];
        toks[tid] = s >> 1;          // k == 2
        gts[tid]  = gates[s];        // gates flat [N*2], index == slot
        eids[tid] = sei[p0 + tid];
    }
    __syncthreads();

    // Stage A: gather 128 token rows, fp32 -> f16 into LDS.
    // Each half-wave (32 lanes) reads one contiguous 512 B row chunk.
    #pragma unroll
    for (int it = 0; it < 16; ++it) {
        int id = it * 256 + tid;         // 0..4095 float4 slots
        int r  = id >> 5;                // row 0..127
        int c4 = id & 31;                // float4 column
        float4 v = ((const float4*)inputs)[(size_t)toks[r] * 32 + c4];
        halfx4 h = { (_Float16)v.x, (_Float16)v.y, (_Float16)v.z, (_Float16)v.w };
        *(halfx4*)&As[r * LSTR + c4 * 4] = h;
    }

    // Barrier + detect whether the whole block is one expert run (common case).
    const int uniform = __syncthreads_and((tid >= TILE_P) || (eids[tid] == eids[0]));

    const int lane = tid & 63;
    const int w    = tid >> 6;       // wave id 0..3
    const int m    = lane & 15;      // row within 16-tile (A) / col within 16-tile (B,D)
    const int q    = lane >> 4;      // quad
    const int c0   = w * 32;         // this wave's output-column base

    int s0 = 0;
    while (s0 < TILE_P) {
        int e, s1;
        if (uniform) { e = eids[0]; s1 = TILE_P; }
        else {
            e = eids[s0]; s1 = s0 + 1;
            while (s1 < TILE_P && eids[s1] == e) ++s1;
        }

        // Load B fragments for weight[e] straight from global (L2-hot, 512 KiB total).
        // B-frag layout: lane holds W[n = c0+ct*16+m][kbase + q*8 + j], j=0..7.
        halfx8 bf[2][4];
        #pragma unroll
        for (int ct = 0; ct < 2; ++ct) {
            const int o = c0 + ct * 16 + m;
            const float* wrow = weight + (size_t)e * (D * D) + (size_t)o * D;
            #pragma unroll
            for (int ks = 0; ks < 4; ++ks) {
                const int col = ks * 32 + q * 8;
                float4 v0 = *(const float4*)(wrow + col);
                float4 v1 = *(const float4*)(wrow + col + 4);
                halfx8 h = { (_Float16)v0.x, (_Float16)v0.y, (_Float16)v0.z, (_Float16)v0.w,
                             (_Float16)v1.x, (_Float16)v1.y, (_Float16)v1.z, (_Float16)v1.w };
                bf[ct][ks] = h;
            }
        }

        floatx4 acc[8][2];
        #pragma unroll
        for (int rt = 0; rt < 8; ++rt) {
            acc[rt][0] = {0.f, 0.f, 0.f, 0.f};
            acc[rt][1] = {0.f, 0.f, 0.f, 0.f};
        }

        #pragma unroll
        for (int ks = 0; ks < 4; ++ks) {
            const int kk = ks * 32 + q * 8;
            #pragma unroll
            for (int rt = 0; rt < 8; ++rt) {
                halfx8 a = *(const halfx8*)&As[(rt * 16 + m) * LSTR + kk];
                acc[rt][0] = __builtin_amdgcn_mfma_f32_16x16x32_f16(a, bf[0][ks], acc[rt][0], 0, 0, 0);
                acc[rt][1] = __builtin_amdgcn_mfma_f32_16x16x32_f16(a, bf[1][ks], acc[rt][1], 0, 0, 0);
            }
        }

        // Epilogue: D row = rt*16 + q*4 + r, col = c0 + ct*16 + m. Only rows in [s0,s1).
        #pragma unroll
        for (int rt = 0; rt < 8; ++rt) {
            #pragma unroll
            for (int r = 0; r < 4; ++r) {
                int row = rt * 16 + q * 4 + r;
                if (row >= s0 && row < s1) {
                    float g = gts[row];
                    float* dst = out + (size_t)toks[row] * D;
                    atomicAdd(dst + c0 + m,      acc[rt][0][r] * g);
                    atomicAdd(dst + c0 + 16 + m, acc[rt][1][r] * g);
                }
            }
        }
        s0 = s1;
    }
}

extern "C" void kernel_launch(void* const* d_in, const int* in_sizes, int n_in,
                              void* d_out, int out_size, void* d_ws, size_t ws_size,
                              hipStream_t stream)
{
    const float* inputs = (const float*)d_in[0];   // [N, 128] fp32
    const float* weight = (const float*)d_in[1];   // [8, 128, 128] fp32
    const float* gates  = (const float*)d_in[2];   // [N, 2] fp32
    // d_in[3] = k (== 2)
    const int*   sei    = (const int*)d_in[4];     // sorted_expert_idxs [N*2]
    const int*   ssi    = (const int*)d_in[5];     // sorted_scattered_idxs [N*2]
    float* out = (float*)d_out;

    // d_out is poisoned before every launch; atomics need zeros.
    hipMemsetAsync(out, 0, (size_t)out_size * sizeof(float), stream);

    moe_mfma_kernel<<<dim3(NK / TILE_P), dim3(256), 0, stream>>>(
        inputs, weight, gates, sei, ssi, out);
}